// Round 1
// baseline (312.251 us; speedup 1.0000x reference)
//
#include <hip/hip_runtime.h>

#define B_DIM 1024
#define T_DIM 512
#define D_IN 32
#define H 64
#define CT 32                 // timesteps per staged X chunk
#define NCHUNK (T_DIM / CT)   // 16

// ---------------------------------------------------------------------------
// Kernel 1: fold embed+ih GEMMs: W_comb = W_ih @ W_emb  [64][32]
//           cvec = W_ih @ b_emb + b_ih + b_hh           [64]
// ---------------------------------------------------------------------------
__global__ __launch_bounds__(1024) void prep_kernel(
    const float* __restrict__ W_emb,  // [H][D_IN]
    const float* __restrict__ b_emb,  // [H]
    const float* __restrict__ W_ih,   // [H][H]
    const float* __restrict__ b_ih,   // [H]
    const float* __restrict__ b_hh,   // [H]
    float* __restrict__ Wc,           // [H][D_IN]
    float* __restrict__ cvec)         // [H]
{
    const int tid = threadIdx.x;
    const int i  = tid >> 4;    // 0..63  output row
    const int dg = tid & 15;    // 0..15  handles d = dg and dg+16
    float s0 = 0.f, s1 = 0.f;
    #pragma unroll
    for (int j = 0; j < H; ++j) {
        const float w = W_ih[i * H + j];
        s0 += w * W_emb[j * D_IN + dg];
        s1 += w * W_emb[j * D_IN + dg + 16];
    }
    Wc[i * D_IN + dg]      = s0;
    Wc[i * D_IN + dg + 16] = s1;
    if (dg == 0) {
        float s = b_ih[i] + b_hh[i];
        #pragma unroll
        for (int j = 0; j < H; ++j) s += W_ih[i * H + j] * b_emb[j];
        cvec[i] = s;
    }
}

// ---------------------------------------------------------------------------
// Kernel 2: fused input-projection + RNN scan + output projection.
// One wave (64 lanes) per batch element; lane i owns hidden unit i.
// ---------------------------------------------------------------------------
__global__ __launch_bounds__(64) void rnn_kernel(
    const float* __restrict__ X,      // [B][T][D_IN]
    const float* __restrict__ W_hh,   // [H][H]
    const float* __restrict__ Wc,     // [H][D_IN]
    const float* __restrict__ cvec,   // [H]
    const float* __restrict__ W_out,  // [1][H]
    const float* __restrict__ b_out,  // [1]
    float* __restrict__ out)          // [B]
{
    __shared__ __align__(16) float xs[2][CT * D_IN];  // 2 x 4 KB staged X
    __shared__ __align__(16) float hs[H];             // hidden state

    const int b = blockIdx.x;
    const int i = threadIdx.x;        // lane 0..63

    // --- per-lane weights into registers ---
    float whh[H];
    #pragma unroll
    for (int j = 0; j < H; j += 4) {
        const float4 v = *(const float4*)&W_hh[i * H + j];
        whh[j] = v.x; whh[j + 1] = v.y; whh[j + 2] = v.z; whh[j + 3] = v.w;
    }
    float wc[D_IN];
    #pragma unroll
    for (int d = 0; d < D_IN; d += 4) {
        const float4 v = *(const float4*)&Wc[i * D_IN + d];
        wc[d] = v.x; wc[d + 1] = v.y; wc[d + 2] = v.z; wc[d + 3] = v.w;
    }
    const float ci = cvec[i];

    const float* __restrict__ xb = X + (size_t)b * T_DIM * D_IN;

    // --- stage chunk 0 (CT*D_IN = 1024 floats; 4 float4 per lane) ---
    {
        float4 st[4];
        #pragma unroll
        for (int k = 0; k < 4; ++k) st[k] = *(const float4*)&xb[k * 256 + i * 4];
        #pragma unroll
        for (int k = 0; k < 4; ++k) *(float4*)&xs[0][k * 256 + i * 4] = st[k];
    }
    hs[i] = 0.f;
    float hlast = 0.f;

    #pragma unroll 1
    for (int c = 0; c < NCHUNK; ++c) {
        const int cur = c & 1;
        // prefetch next chunk into registers (HBM latency hides under compute)
        float4 pf[4];
        if (c + 1 < NCHUNK) {
            #pragma unroll
            for (int k = 0; k < 4; ++k)
                pf[k] = *(const float4*)&xb[(c + 1) * (CT * D_IN) + k * 256 + i * 4];
        }

        #pragma unroll 2
        for (int tt = 0; tt < CT; ++tt) {
            const float* __restrict__ xrow = &xs[cur][tt * D_IN];
            // 4-way split accumulators to break the serial FMA chain
            float a0 = ci, a1 = 0.f, a2 = 0.f, a3 = 0.f;
            #pragma unroll
            for (int d = 0; d < D_IN; d += 4) {
                const float4 xv = *(const float4*)&xrow[d];   // wave-broadcast LDS read
                a0 += wc[d]     * xv.x;
                a1 += wc[d + 1] * xv.y;
                a2 += wc[d + 2] * xv.z;
                a3 += wc[d + 3] * xv.w;
            }
            #pragma unroll
            for (int j = 0; j < H; j += 4) {
                const float4 hv = *(const float4*)&hs[j];     // wave-broadcast LDS read
                a0 += whh[j]     * hv.x;
                a1 += whh[j + 1] * hv.y;
                a2 += whh[j + 2] * hv.z;
                a3 += whh[j + 3] * hv.w;
            }
            const float acc = (a0 + a1) + (a2 + a3);
            // tanh(x) = 1 - 2/(exp(2x)+1); saturates correctly at +/-inf
            const float e  = __builtin_amdgcn_exp2f(acc * 2.885390081777927f); // 2*log2(e)
            const float hn = __builtin_fmaf(-2.f, __builtin_amdgcn_rcpf(e + 1.f), 1.f);
            hs[i] = hn;               // single wave: compiler-ordered via lgkmcnt
            hlast = hn;
        }

        // store prefetched chunk into the other buffer
        if (c + 1 < NCHUNK) {
            const int nxt = cur ^ 1;
            #pragma unroll
            for (int k = 0; k < 4; ++k)
                *(float4*)&xs[nxt][k * 256 + i * 4] = pf[k];
        }
    }

    // --- output projection: out[b] = dot(hT, W_out) + b_out ---
    float val = hlast * W_out[i];
    #pragma unroll
    for (int off = 32; off > 0; off >>= 1)
        val += __shfl_xor(val, off, 64);
    if (i == 0) out[b] = val + b_out[0];
}

// ---------------------------------------------------------------------------
extern "C" void kernel_launch(void* const* d_in, const int* in_sizes, int n_in,
                              void* d_out, int out_size, void* d_ws, size_t ws_size,
                              hipStream_t stream) {
    const float* X     = (const float*)d_in[0];
    const float* W_emb = (const float*)d_in[1];
    const float* b_emb = (const float*)d_in[2];
    const float* W_ih  = (const float*)d_in[3];
    const float* b_ih  = (const float*)d_in[4];
    const float* W_hh  = (const float*)d_in[5];
    const float* b_hh  = (const float*)d_in[6];
    const float* W_out = (const float*)d_in[7];
    const float* b_out = (const float*)d_in[8];
    float* out = (float*)d_out;

    float* Wc   = (float*)d_ws;                 // 64*32 floats = 8 KB
    float* cvec = (float*)d_ws + H * D_IN;      // 64 floats

    prep_kernel<<<1, 1024, 0, stream>>>(W_emb, b_emb, W_ih, b_ih, b_hh, Wc, cvec);
    rnn_kernel<<<B_DIM, 64, 0, stream>>>(X, W_hh, Wc, cvec, W_out, b_out, out);
}